// Round 17
// baseline (437.462 us; speedup 1.0000x reference)
//
#include <hip/hip_runtime.h>
#include <hip/hip_bf16.h>
#include <cstdint>
#include <type_traits>

#define N_NODES 100000
#define N_EDGES 500000
#define FEAT 128
#define HID 256
#define N_LINKS 16384
#define BCAP 32   // bucket capacity; deg ~ Poisson(5), P(>32) ~ 1e-15

typedef __attribute__((ext_vector_type(8))) short short8;     // 8 bf16 = 4 VGPRs
typedef __attribute__((ext_vector_type(4))) float floatx4;
typedef __attribute__((ext_vector_type(16))) float floatx16;  // 32x32 acc

// ---- scalar load/store ----
__device__ __forceinline__ float ldf(const float* p) { return *p; }
__device__ __forceinline__ float ldf(const __hip_bfloat16* p) { return __bfloat162float(*p); }
__device__ __forceinline__ void stf(float* p, float v) { *p = v; }
__device__ __forceinline__ void stf(__hip_bfloat16* p, float v) { *p = __float2bfloat16(v); }

// 4-wide bf16 load/store (8B)
__device__ __forceinline__ void load4(const __hip_bfloat16* p, float v[4]) {
    const uint2 q = *(const uint2*)p;
    v[0] = __uint_as_float(q.x << 16);
    v[1] = __uint_as_float(q.x & 0xffff0000u);
    v[2] = __uint_as_float(q.y << 16);
    v[3] = __uint_as_float(q.y & 0xffff0000u);
}
__device__ __forceinline__ void store4(__hip_bfloat16* p, const float v[4]) {
    __hip_bfloat16 b[4];
    b[0] = __float2bfloat16(v[0]); b[1] = __float2bfloat16(v[1]);
    b[2] = __float2bfloat16(v[2]); b[3] = __float2bfloat16(v[3]);
    *(uint2*)p = *(const uint2*)b;
}

// 8-wide bf16 load/store (16B)
__device__ __forceinline__ void load8(const __hip_bfloat16* p, float v[8]) {
    const uint4 q = *(const uint4*)p;
    v[0] = __uint_as_float(q.x << 16);
    v[1] = __uint_as_float(q.x & 0xffff0000u);
    v[2] = __uint_as_float(q.y << 16);
    v[3] = __uint_as_float(q.y & 0xffff0000u);
    v[4] = __uint_as_float(q.z << 16);
    v[5] = __uint_as_float(q.z & 0xffff0000u);
    v[6] = __uint_as_float(q.w << 16);
    v[7] = __uint_as_float(q.w & 0xffff0000u);
}
__device__ __forceinline__ void store8(__hip_bfloat16* p, const float v[8]) {
    __hip_bfloat16 b[8];
    #pragma unroll
    for (int i = 0; i < 8; i++) b[i] = __float2bfloat16(v[i]);
    *(uint4*)p = *(const uint4*)b;
}

// unpack a raw 16B bf16x8 chunk into fp32[8]
__device__ __forceinline__ void unpack8(const uint4& q, float v[8]) {
    v[0] = __uint_as_float(q.x << 16);
    v[1] = __uint_as_float(q.x & 0xffff0000u);
    v[2] = __uint_as_float(q.y << 16);
    v[3] = __uint_as_float(q.y & 0xffff0000u);
    v[4] = __uint_as_float(q.z << 16);
    v[5] = __uint_as_float(q.z & 0xffff0000u);
    v[6] = __uint_as_float(q.w << 16);
    v[7] = __uint_as_float(q.w & 0xffff0000u);
}

// unpack a raw 16B bf16x8 chunk and accumulate into acc[8]
__device__ __forceinline__ void acc8(const uint4& q, float a[8]) {
    a[0] += __uint_as_float(q.x << 16);
    a[1] += __uint_as_float(q.x & 0xffff0000u);
    a[2] += __uint_as_float(q.y << 16);
    a[3] += __uint_as_float(q.y & 0xffff0000u);
    a[4] += __uint_as_float(q.z << 16);
    a[5] += __uint_as_float(q.z & 0xffff0000u);
    a[6] += __uint_as_float(q.w << 16);
    a[7] += __uint_as_float(q.w & 0xffff0000u);
}

// async global->LDS, 16B per lane; LDS dest = wave-uniform base + lane*16
__device__ __forceinline__ void gload_lds16(const short* g, short* lds) {
    __builtin_amdgcn_global_load_lds(
        reinterpret_cast<const __attribute__((address_space(1))) unsigned int*>(
            reinterpret_cast<uintptr_t>(g)),
        reinterpret_cast<__attribute__((address_space(3))) unsigned int*>(
            reinterpret_cast<uintptr_t>(lds)),
        16, 0, 0);
}

// defensive: any out-of-range index becomes 0 (wrong answer, not a fault)
__device__ __forceinline__ int clampi(int v, int n) { return ((unsigned)v < (unsigned)n) ? v : 0; }

// ---------------- utility ----------------

__global__ void zero_f32(float* p, int n) {
    int i = blockIdx.x * blockDim.x + threadIdx.x;
    if (i < n) p[i] = 0.0f;
}

// packed "LDS image" layout for all staged B operands.
// Per matrix: [KS/8 ksegs][256 cols][8 bf16], element (kseg, n, j) = W[n][kseg*8+j].
#define POF_EMB 0
#define POF_L0  32768
#define POF_R0  98304
#define POF_L1  163840
#define POF_R1  229376
#define POF_P1  294912
#define WP_ALL  557056     // + 256*1024 for wp1

// R28: prep_all gains a 4th range: pad-init ebuf with N_NODES (zero-row idx)
// so gather's 16-slot prefix has deg-independent addresses.
#define CVTX_NB 12500                        // (N_NODES*FEAT/4)/256, exact
#define INIT_NB ((N_NODES + 255) / 256)      // 391
#define CVTW_NB (WP_ALL / 256)               // 2176, exact
#define EBUF_NB ((N_NODES * BCAP / 4) / 256) // 3125 (int4 stores, exact)
__global__ void prep_all(const float4* __restrict__ x, __hip_bfloat16* __restrict__ xb,
                         int* __restrict__ deg, int* __restrict__ h0pad,
                         int* __restrict__ h1pad,
                         const float* __restrict__ w_emb, const float* __restrict__ wl0,
                         const float* __restrict__ wr0, const float* __restrict__ wl1,
                         const float* __restrict__ wr1, const float* __restrict__ wp1,
                         __hip_bfloat16* __restrict__ wbp, int4* __restrict__ ebuf4) {
    int b = blockIdx.x;
    if (b < CVTX_NB) {
        int i = b * 256 + threadIdx.x;
        float4 v = x[i];
        float a[4] = {v.x, v.y, v.z, v.w};
        store4(&xb[(size_t)i * 4], a);
    } else if (b < CVTX_NB + INIT_NB) {
        int i = (b - CVTX_NB) * 256 + threadIdx.x;
        if (i < N_NODES) deg[i] = 0;
        if (i < 128) { h0pad[i] = 0; h1pad[i] = 0; }
    } else if (b < CVTX_NB + INIT_NB + CVTW_NB) {
        int i = (b - CVTX_NB - INIT_NB) * 256 + threadIdx.x;
        if (i < WP_ALL) {
            const float* src; int off, ks;
            if      (i < POF_L0) { src = w_emb; off = POF_EMB; ks = 128; }
            else if (i < POF_R0) { src = wl0;   off = POF_L0;  ks = 256; }
            else if (i < POF_L1) { src = wr0;   off = POF_R0;  ks = 256; }
            else if (i < POF_R1) { src = wl1;   off = POF_L1;  ks = 256; }
            else if (i < POF_P1) { src = wr1;   off = POF_R1;  ks = 256; }
            else                 { src = wp1;   off = POF_P1;  ks = 1024; }
            int o = i - off;
            int kseg = o >> 11;
            int rem  = o & 2047;
            int n = rem >> 3, j = rem & 7;
            wbp[i] = __float2bfloat16(src[n * ks + kseg * 8 + j]);
        }
    } else {
        int i = (b - CVTX_NB - INIT_NB - CVTW_NB) * 256 + threadIdx.x;
        ebuf4[i] = make_int4(N_NODES, N_NODES, N_NODES, N_NODES);   // pad slots
    }
}

// ---------------- bucketed adjacency build ----------------
// ebuf[n*BCAP + pos]; pos from atomicAdd(&deg[n]) -> count+fill in ONE kernel.
// Arrival order varies per run -> sort_rows normalizes (ascending src per
// node) -> bit-exact aggregation. Slots >= deg keep the N_NODES pad.

__global__ void fill_buckets(const int* __restrict__ src, const int* __restrict__ dst,
                             int* __restrict__ deg, int* __restrict__ ebuf, int nE) {
    int e = blockIdx.x * blockDim.x + threadIdx.x;
    if (e >= nE) return;
    int d = clampi(dst[e], N_NODES);
    int pos = atomicAdd(&deg[d], 1);
    if (pos < BCAP) ebuf[d * BCAP + pos] = clampi(src[e], N_NODES);
}

__global__ void sort_rows(const int* __restrict__ deg, int* __restrict__ ebuf) {
    int n = blockIdx.x * blockDim.x + threadIdx.x;
    if (n >= N_NODES) return;
    int dg = deg[n]; if (dg > BCAP) dg = BCAP;
    int start = n * BCAP, end = start + dg;
    for (int i = start + 1; i < end; i++) {          // insertion sort (mean deg ~5)
        int key = ebuf[i];
        int j = i - 1;
        while (j >= start && ebuf[j] > key) { ebuf[j + 1] = ebuf[j]; j--; }
        ebuf[j + 1] = key;
    }
}

// ---------------- gather aggregation ----------------
// R28: the 50us residual (vs ~31us traffic floor) was the 3-deep serial
// chain deg -> ebuf-addr -> row. Bucket rows are now PRE-PADDED with
// N_NODES (zero row), so the first 16 slot addresses are deg-INDEPENDENT:
// issue all 16 ebuf loads + self + deg at once, then 16 row loads (pads
// broadcast-hit the L2-resident zero row), then unconditional accumulate
// (+0.0 exact). Chain = 2 latencies for 99.998% of nodes; rare deg>16
// tail uses the old guarded loop (slots ascending) -> sums bit-identical,
// deterministic.

__global__ __launch_bounds__(256) void gather_agg(const __hip_bfloat16* __restrict__ h,
                                                  const int* __restrict__ deg,
                                                  const int* __restrict__ ebuf,
                                                  __hip_bfloat16* __restrict__ agg) {
    int wave = threadIdx.x >> 6, lane = threadIdx.x & 63;
    int half = lane >> 5, l32 = lane & 31;
    int n = blockIdx.x * 8 + wave * 2 + half;       // 8 nodes per 256-thr block
    bool active = (n < N_NODES);
    int nn = active ? n : 0;
    int start = nn * BCAP;

    // deg-independent issue: 16 slot indices (fixed addrs) + self row
    int idx[16];
    #pragma unroll
    for (int i = 0; i < 16; i++) idx[i] = ebuf[start + i];
    int dg = active ? deg[nn] : 0;

    float acc[8];
    {
        float sv[8];
        load8(&h[(long long)nn * HID + l32 * 8], sv);   // self row
        #pragma unroll
        for (int k = 0; k < 8; k++) acc[k] = sv[k];
    }

    // branch-free 16-slot prefix (pads -> zero row, +0.0 exact)
    uint4 rawA[8], rawB[8];
    #pragma unroll
    for (int i = 0; i < 8; i++)
        rawA[i] = *(const uint4*)&h[(long long)idx[i] * HID + l32 * 8];
    #pragma unroll
    for (int i = 0; i < 8; i++)
        rawB[i] = *(const uint4*)&h[(long long)idx[8 + i] * HID + l32 * 8];
    #pragma unroll
    for (int i = 0; i < 8; i++) acc8(rawA[i], acc);
    #pragma unroll
    for (int i = 0; i < 8; i++) acc8(rawB[i], acc);

    // rare tail: deg > 16 (exec-masked; slots ascending, pads +0.0)
    int dgc = dg > BCAP ? BCAP : dg;
    int end = start + dgc;
    for (int e = start + 16; e < end; e += 8) {
        int cnt = end - e;
        uint4 raw[8];
        #pragma unroll
        for (int i = 0; i < 8; i++) {
            int t = e + i; t = (t < end) ? t : (end - 1);
            int s2 = (i < cnt) ? ebuf[t] : N_NODES;
            raw[i] = *(const uint4*)&h[(long long)s2 * HID + l32 * 8];
        }
        #pragma unroll
        for (int i = 0; i < 8; i++) acc8(raw[i], acc);
    }

    float inv = 1.0f / (float)(dg + 1);
    #pragma unroll
    for (int k = 0; k < 8; k++) acc[k] *= inv;
    if (active) store8(&agg[(long long)n * HID + l32 * 8], acc);
}

// ============ R22/R25: K-concat LDS-staged GEMM, BK=64 (verified optimum) ============
// C = [A1|A2] @ [B1|B2]^T as ONE K=512 GEMM. Block = 128 rows x 128 cols
// (cg in {0,1}), 4 waves x (32x128) -> acc[4]; 16 MFMA per barrier.
// Grid (GX=256, 2): 512 blocks = 2/CU; cg duplicates 256 apart -> same XCD L2.
// A XOR-swizzled via pre-swizzled global source; B from packed image;
// 2-phase __syncthreads pipeline. MFMA order: t asc, k16 asc -> bit-exact.

template <int KS, bool DUAL, typename TC, bool RELU>
__global__ __launch_bounds__(256, 2) void gemm_kc(const __hip_bfloat16* __restrict__ A1,
                                                  const __hip_bfloat16* __restrict__ A2,
                                                  const __hip_bfloat16* __restrict__ Bp1,
                                                  const __hip_bfloat16* __restrict__ Bp2,
                                                  const float* __restrict__ bias,
                                                  TC* __restrict__ C, int M, int GX) {
    const int N = 256;
    const int NSTEP = (DUAL ? 2 : 1) * KS / 64;       // 64-wide K steps
    __shared__ __align__(16) short As[2][128 * 64];   // 2 x 16 KB
    __shared__ __align__(16) short Bs[2][64 * 128];   // 2 x 16 KB  (64 KB total)

    const int tid = threadIdx.x;
    const int w = tid >> 6, lane = tid & 63;
    const int half = lane >> 5, l32 = lane & 31;
    const int cg = blockIdx.y;                        // 0..1 (128-col groups)

    const short* A1s = (const short*)A1;
    const short* A2s = (const short*)A2;
    const short* B1s = (const short*)Bp1;
    const short* B2s = (const short*)Bp2;

    const int NT = (M + 127) / 128;
    for (int tile = blockIdx.x; tile < NT; tile += GX) {
        const int row0 = tile * 128;

        // stage K-step t: A 4 gloads/thread, B 4 gloads/thread
        auto stage = [&](int buf, int t) {
            const short* Asrc; const short* Bsrc; int kl;
            if (!DUAL || t < KS / 64) { Asrc = A1s; Bsrc = B1s; kl = t * 64; }
            else                      { Asrc = A2s; Bsrc = B2s; kl = t * 64 - KS; }
            #pragma unroll
            for (int i = 0; i < 4; i++) {
                int idx = i * 256 + tid;             // 0..1023
                int row = idx >> 3, b16 = idx & 7;
                int gr = row0 + row; if (gr >= M) gr = M - 1;
                gload_lds16(Asrc + (size_t)gr * KS + kl + ((b16 ^ (row & 7)) * 8),
                            (short*)&As[buf][idx * 8]);
            }
            #pragma unroll
            for (int i = 0; i < 4; i++) {
                int idx = i * 256 + tid;             // 0..1023
                int kseg = idx >> 7, col = idx & 127;
                gload_lds16(Bsrc + ((size_t)((kl >> 3) + kseg) * 256 + cg * 128 + col) * 8,
                            (short*)&Bs[buf][idx * 8]);
            }
        };

        floatx16 acc[4] = {};
        int cur = 0;
        stage(0, 0);
        __syncthreads();

        for (int t = 0; t < NSTEP; t++) {
            if (t + 1 < NSTEP) stage(cur ^ 1, t + 1);   // async, overlaps compute

            const int arow = w * 32 + l32;
            #pragma unroll
            for (int k16 = 0; k16 < 4; k16++) {
                int e = k16 * 2 + half;
                short8 a = *(const short8*)&As[cur][(arow * 8 + (e ^ (l32 & 7))) * 8];
                #pragma unroll
                for (int ct = 0; ct < 4; ct++) {
                    short8 b = *(const short8*)&Bs[cur][(e * 128 + ct * 32 + l32) * 8];
                    acc[ct] = __builtin_amdgcn_mfma_f32_32x32x16_bf16(a, b, acc[ct], 0, 0, 0);
                }
            }
            __syncthreads();                            // vmcnt(0)+lgkm+barrier
            cur ^= 1;
        }

        // epilogue: C/D col = lane&31, row = (reg&3) + 8*(reg>>2) + 4*half
        #pragma unroll
        for (int ct = 0; ct < 4; ct++) {
            int c = cg * 128 + ct * 32 + l32;
            float bc = bias[c];
            #pragma unroll
            for (int reg = 0; reg < 16; reg++) {
                int rr = row0 + w * 32 + (reg & 3) + 8 * (reg >> 2) + 4 * half;
                if (rr < M) {
                    float v = acc[ct][reg] + bc;
                    if (RELU) v = fmaxf(v, 0.0f);
                    stf(&C[(size_t)rr * N + c], v);
                }
            }
        }
    }
}

// ---------------- prediction head (R25: register-resident A, 4-step chunks) ----------------
// Each lane PRELOADS its full A-side data once: s/d row slices (cols
// quad*8 + j*32, j=0..7) as uint4 sraw[8]/draw[8]. Per step the A fragment
// is register-only: seg0/1 = reinterpret; seg2/3 = unpack->mul/absdiff->pack
// (same fp32->bf16 rounding as materialized comb -> bit-identical). B staged
// in 4-step chunks (16 KB x2 LDS) -> 8 barrier pairs, 16 MFMA/wave each.
// MFMA order: global step ascending (k ascending) -> bit-exact.

__global__ __launch_bounds__(256, 3) void pred_gemm(const __hip_bfloat16* __restrict__ h,
                                                    const int* __restrict__ src_idx,
                                                    const int* __restrict__ dst_idx,
                                                    const __hip_bfloat16* __restrict__ Bp,
                                                    const float* __restrict__ bias,
                                                    float* __restrict__ C, int M) {
    const int N = 256;
    __shared__ __align__(16) short Bs[2][16 * 64 * 8];   // 2 x 16 KB

    int w = threadIdx.x >> 6, lane = threadIdx.x & 63;
    int quad = lane >> 4, l16 = lane & 15;
    int cg = blockIdx.y;                    // 0..3 (64-col groups)
    int row0 = blockIdx.x * 64 + w * 16;    // wave owns 16 rows

    const short* Bps = (const short*)Bp;

    int rr = row0 + l16;
    int r = rr < M ? rr : M - 1;
    int sidx = clampi(src_idx[r], N_NODES);
    int didx = clampi(dst_idx[r], N_NODES);

    // one-time preload of this lane's s/d slices (64 bf16 each)
    uint4 sraw[8], draw[8];
    #pragma unroll
    for (int j = 0; j < 8; j++) {
        sraw[j] = *(const uint4*)&h[(size_t)sidx * HID + quad * 8 + j * 32];
        draw[j] = *(const uint4*)&h[(size_t)didx * HID + quad * 8 + j * 32];
    }

    // stage one 4-step chunk (16 local ksegs) of the 64-col B slice
    auto stageB = [&](int buf, int chunk) {
        #pragma unroll
        for (int i = 0; i < 4; i++) {
            int idx = i * 256 + (int)threadIdx.x;    // 0..1023
            int ks = idx >> 6, col = idx & 63;       // local kseg 0..15
            gload_lds16(Bps + ((size_t)(chunk * 16 + ks) * 256 + cg * 64 + col) * 8,
                        (short*)&Bs[buf][idx * 8]);
        }
    };

    floatx4 acc[4] = {};
    stageB(0, 0);
    __syncthreads();
    int cur = 0;

    #pragma unroll
    for (int c = 0; c < 8; c++) {             // chunk = 4 K-steps; seg = c>>1
        if (c + 1 < 8) stageB(cur ^ 1, c + 1);

        #pragma unroll
        for (int s = 0; s < 4; s++) {
            const int j = ((c & 1) ? 4 : 0) + s;   // global step t = 4c+s; j = t&7
            short8 a;
            if (c < 2) {
                a = *(const short8*)&sraw[j];
            } else if (c < 4) {
                a = *(const short8*)&draw[j];
            } else {
                float sv[8], dv[8];
                unpack8(sraw[j], sv);
                unpack8(draw[j], dv);
                __hip_bfloat16 b8[8];
                if (c < 6) {
                    #pragma unroll
                    for (int q = 0; q < 8; q++) b8[q] = __float2bfloat16(sv[q] * dv[q]);
                } else {
                    #pragma unroll
                    for (int q = 0; q < 8; q++) b8[q] = __float2bfloat16(fabsf(sv[q] - dv[q]));
                }
                a = *(const short8*)b8;
            }
            #pragma unroll
            for (int ct = 0; ct < 4; ct++) {
                short8 b = *(const short8*)&Bs[cur][((s * 4 + quad) * 64 + ct * 16 + l16) * 8];
                acc[ct] = __builtin_amdgcn_mfma_f32_16x16x32_bf16(a, b, acc[ct], 0, 0, 0);
            }
        }
        __syncthreads();
        cur ^= 1;
    }

    // epilogue: col = l16-based, row = quad*4 + i
    #pragma unroll
    for (int ct = 0; ct < 4; ct++) {
        int c = cg * 64 + ct * 16 + l16;
        float bc = bias[c];
        #pragma unroll
        for (int i = 0; i < 4; i++) {
            int r2 = row0 + quad * 4 + i;
            if (r2 < M) C[(size_t)r2 * N + c] = fmaxf(acc[ct][i] + bc, 0.0f);
        }
    }
}

__global__ __launch_bounds__(256) void pred_final(const float* __restrict__ hidden,
                                                  const float* __restrict__ wp2,
                                                  const float* __restrict__ bp2,
                                                  float* __restrict__ out) {
    int wave = threadIdx.x >> 6;
    int lane = threadIdx.x & 63;
    int row = blockIdx.x * 4 + wave;
    if (row >= N_LINKS) return;
    const float4 hv = *(const float4*)&hidden[(long long)row * HID + lane * 4];
    const float4 wv = *(const float4*)&wp2[lane * 4];
    float v = hv.x * wv.x + hv.y * wv.y + hv.z * wv.z + hv.w * wv.w;
    #pragma unroll
    for (int off = 32; off > 0; off >>= 1) v += __shfl_down(v, off, 64);
    if (lane == 0) out[row] = 1.0f / (1.0f + expf(-(v + bp2[0])));
}

// ---------------- launch ----------------

extern "C" void kernel_launch(void* const* d_in, const int* in_sizes, int n_in,
                              void* d_out, int out_size, void* d_ws, size_t ws_size,
                              hipStream_t stream) {
    const float* x          = (const float*)d_in[0];
    const int*   edge_index = (const int*)d_in[1];
    const int*   e_src      = edge_index;            // row 0
    const int*   e_dst      = edge_index + N_EDGES;  // row 1
    const int*   src_idx    = (const int*)d_in[3];
    const int*   dst_idx    = (const int*)d_in[4];
    const float* w_emb      = (const float*)d_in[5];
    const float* b_emb      = (const float*)d_in[6];
    const float* wl0        = (const float*)d_in[8];
    const float* bl0        = (const float*)d_in[9];
    const float* wr0        = (const float*)d_in[10];
    const float* wl1        = (const float*)d_in[13];
    const float* bl1        = (const float*)d_in[14];
    const float* wr1        = (const float*)d_in[15];
    const float* wp1        = (const float*)d_in[18];
    const float* bp1        = (const float*)d_in[19];
    const float* wp2        = (const float*)d_in[20];
    const float* bp2        = (const float*)d_in[21];
    float* out = (float*)d_out;

    typedef __hip_bfloat16 bf16;
    const size_t NH  = (size_t)N_NODES * HID;
    const size_t NH1 = (size_t)(N_NODES + 1) * HID;   // +1 zero row (gather pads)

    // workspace plan (~194 MB; ws proven >= 205 MB)
    char* p = (char*)d_ws;
    bf16* h0   = (bf16*)p;  p += NH1 * 2;                      // 51.2 MB (+512B)
    bf16* h1   = (bf16*)p;  p += NH1 * 2;                      // 51.2 MB (+512B)
    bf16* agg  = (bf16*)p;  p += NH * 2;                       // 51.2 MB
    bf16* xb   = (bf16*)p;  p += (size_t)N_NODES * FEAT * 2;   // 25.6 MB
    bf16* wbp  = (bf16*)p;  p += (size_t)WP_ALL * 2;           // 1.1 MB (packed)
    p = (char*)(((uintptr_t)p + 255) & ~(uintptr_t)255);
    int* deg  = (int*)p; p += (size_t)N_NODES * 4;             // 0.4 MB
    int* ebuf = (int*)p; p += (size_t)N_NODES * BCAP * 4;      // 12.8 MB
    const size_t need = (size_t)(p - (char*)d_ws);

    if (ws_size < need) {   // visible failure, no fault
        zero_f32<<<(out_size + 255) / 256, 256, 0, stream>>>(out, out_size);
        return;
    }

    // alias (region dead by the time it's reused):
    float* hidden = (float*)h1;  // [16384][256] fp32 = 16.8 MB <= 51.2

    // ---- fused prep (cvt_x | deg/pad init | weight pack | ebuf pad) ----
    prep_all<<<CVTX_NB + INIT_NB + CVTW_NB + EBUF_NB, 256, 0, stream>>>(
        (const float4*)x, xb, deg, (int*)(h0 + NH), (int*)(h1 + NH),
        w_emb, wl0, wr0, wl1, wr1, wp1, wbp, (int4*)ebuf);

    // ---- bucketed adjacency ----
    fill_buckets<<<(N_EDGES + 255) / 256, 256, 0, stream>>>(e_src, e_dst, deg, ebuf, N_EDGES);
    sort_rows<<<(N_NODES + 255) / 256, 256, 0, stream>>>(deg, ebuf);

    const int GX = 256;                     // 256 walkers x 2 cg = 512 blocks, 2/CU
    dim3 pgrid(GX, 2);                      // cg slow; duplicates 256 apart ->
                                            // same XCD L2 (256 % 8 == 0)

    // ---- embedding: h0 = xb @ w_emb^T + b_emb  (KS=128) ----
    gemm_kc<128, false, bf16, false><<<pgrid, 256, 0, stream>>>(
        xb, nullptr, wbp + POF_EMB, nullptr, b_emb, h0, N_NODES, GX);

    // ---- layer 0: h1 = relu(agg@wl0^T + bl0 + h0@wr0^T)  (K-concat 512) ----
    gather_agg<<<(N_NODES + 7) / 8, 256, 0, stream>>>(h0, deg, ebuf, agg);
    gemm_kc<256, true, bf16, true><<<pgrid, 256, 0, stream>>>(
        agg, h0, wbp + POF_L0, wbp + POF_R0, bl0, h1, N_NODES, GX);

    // ---- layer 1: h0 = relu(agg@wl1^T + bl1 + h1@wr1^T) ----
    gather_agg<<<(N_NODES + 7) / 8, 256, 0, stream>>>(h1, deg, ebuf, agg);
    gemm_kc<256, true, bf16, true><<<pgrid, 256, 0, stream>>>(
        agg, h1, wbp + POF_L1, wbp + POF_R1, bl1, h0, N_NODES, GX);

    // ---- prediction head (comb fused; register-resident A) ----
    dim3 pgrid2(N_LINKS / 64, 4);
    pred_gemm<<<pgrid2, 256, 0, stream>>>(
        h0, src_idx, dst_idx, wbp + POF_P1, bp1, hidden, N_LINKS);
    pred_final<<<N_LINKS / 4, 256, 0, stream>>>(hidden, wp2, bp2, out);
}

// Round 18
// 425.928 us; speedup vs baseline: 1.0271x; 1.0271x over previous
//
#include <hip/hip_runtime.h>
#include <hip/hip_bf16.h>
#include <cstdint>
#include <type_traits>

#define N_NODES 100000
#define N_EDGES 500000
#define FEAT 128
#define HID 256
#define N_LINKS 16384
#define BCAP 32   // bucket capacity; deg ~ Poisson(5), P(>32) ~ 1e-15

typedef __attribute__((ext_vector_type(8))) short short8;     // 8 bf16 = 4 VGPRs
typedef __attribute__((ext_vector_type(4))) float floatx4;
typedef __attribute__((ext_vector_type(16))) float floatx16;  // 32x32 acc

// ---- scalar load/store ----
__device__ __forceinline__ float ldf(const float* p) { return *p; }
__device__ __forceinline__ float ldf(const __hip_bfloat16* p) { return __bfloat162float(*p); }
__device__ __forceinline__ void stf(float* p, float v) { *p = v; }
__device__ __forceinline__ void stf(__hip_bfloat16* p, float v) { *p = __float2bfloat16(v); }

// 4-wide bf16 load/store (8B)
__device__ __forceinline__ void load4(const __hip_bfloat16* p, float v[4]) {
    const uint2 q = *(const uint2*)p;
    v[0] = __uint_as_float(q.x << 16);
    v[1] = __uint_as_float(q.x & 0xffff0000u);
    v[2] = __uint_as_float(q.y << 16);
    v[3] = __uint_as_float(q.y & 0xffff0000u);
}
__device__ __forceinline__ void store4(__hip_bfloat16* p, const float v[4]) {
    __hip_bfloat16 b[4];
    b[0] = __float2bfloat16(v[0]); b[1] = __float2bfloat16(v[1]);
    b[2] = __float2bfloat16(v[2]); b[3] = __float2bfloat16(v[3]);
    *(uint2*)p = *(const uint2*)b;
}

// 8-wide bf16 load/store (16B)
__device__ __forceinline__ void load8(const __hip_bfloat16* p, float v[8]) {
    const uint4 q = *(const uint4*)p;
    v[0] = __uint_as_float(q.x << 16);
    v[1] = __uint_as_float(q.x & 0xffff0000u);
    v[2] = __uint_as_float(q.y << 16);
    v[3] = __uint_as_float(q.y & 0xffff0000u);
    v[4] = __uint_as_float(q.z << 16);
    v[5] = __uint_as_float(q.z & 0xffff0000u);
    v[6] = __uint_as_float(q.w << 16);
    v[7] = __uint_as_float(q.w & 0xffff0000u);
}
__device__ __forceinline__ void store8(__hip_bfloat16* p, const float v[8]) {
    __hip_bfloat16 b[8];
    #pragma unroll
    for (int i = 0; i < 8; i++) b[i] = __float2bfloat16(v[i]);
    *(uint4*)p = *(const uint4*)b;
}

// unpack a raw 16B bf16x8 chunk into fp32[8]
__device__ __forceinline__ void unpack8(const uint4& q, float v[8]) {
    v[0] = __uint_as_float(q.x << 16);
    v[1] = __uint_as_float(q.x & 0xffff0000u);
    v[2] = __uint_as_float(q.y << 16);
    v[3] = __uint_as_float(q.y & 0xffff0000u);
    v[4] = __uint_as_float(q.z << 16);
    v[5] = __uint_as_float(q.z & 0xffff0000u);
    v[6] = __uint_as_float(q.w << 16);
    v[7] = __uint_as_float(q.w & 0xffff0000u);
}

// unpack a raw 16B bf16x8 chunk and accumulate into acc[8]
__device__ __forceinline__ void acc8(const uint4& q, float a[8]) {
    a[0] += __uint_as_float(q.x << 16);
    a[1] += __uint_as_float(q.x & 0xffff0000u);
    a[2] += __uint_as_float(q.y << 16);
    a[3] += __uint_as_float(q.y & 0xffff0000u);
    a[4] += __uint_as_float(q.z << 16);
    a[5] += __uint_as_float(q.z & 0xffff0000u);
    a[6] += __uint_as_float(q.w << 16);
    a[7] += __uint_as_float(q.w & 0xffff0000u);
}

// async global->LDS, 16B per lane; LDS dest = wave-uniform base + lane*16
__device__ __forceinline__ void gload_lds16(const short* g, short* lds) {
    __builtin_amdgcn_global_load_lds(
        reinterpret_cast<const __attribute__((address_space(1))) unsigned int*>(
            reinterpret_cast<uintptr_t>(g)),
        reinterpret_cast<__attribute__((address_space(3))) unsigned int*>(
            reinterpret_cast<uintptr_t>(lds)),
        16, 0, 0);
}

// defensive: any out-of-range index becomes 0 (wrong answer, not a fault)
__device__ __forceinline__ int clampi(int v, int n) { return ((unsigned)v < (unsigned)n) ? v : 0; }

// ---------------- utility ----------------

__global__ void zero_f32(float* p, int n) {
    int i = blockIdx.x * blockDim.x + threadIdx.x;
    if (i < n) p[i] = 0.0f;
}

// packed "LDS image" layout for all staged B operands.
// Per matrix: [KS/8 ksegs][256 cols][8 bf16], element (kseg, n, j) = W[n][kseg*8+j].
#define POF_EMB 0
#define POF_L0  32768
#define POF_R0  98304
#define POF_L1  163840
#define POF_R1  229376
#define POF_P1  294912
#define WP_ALL  557056     // + 256*1024 for wp1

// prep_all: cvt_x | deg/pad init | weight pack | ebuf pad — 4 disjoint ranges.
#define CVTX_NB 12500                        // (N_NODES*FEAT/4)/256, exact
#define INIT_NB ((N_NODES + 255) / 256)      // 391
#define CVTW_NB (WP_ALL / 256)               // 2176, exact
#define EBUF_NB ((N_NODES * BCAP / 4) / 256) // 3125 (int4 stores, exact)
__global__ void prep_all(const float4* __restrict__ x, __hip_bfloat16* __restrict__ xb,
                         int* __restrict__ deg, int* __restrict__ h0pad,
                         int* __restrict__ h1pad,
                         const float* __restrict__ w_emb, const float* __restrict__ wl0,
                         const float* __restrict__ wr0, const float* __restrict__ wl1,
                         const float* __restrict__ wr1, const float* __restrict__ wp1,
                         __hip_bfloat16* __restrict__ wbp, int4* __restrict__ ebuf4) {
    int b = blockIdx.x;
    if (b < CVTX_NB) {
        int i = b * 256 + threadIdx.x;
        float4 v = x[i];
        float a[4] = {v.x, v.y, v.z, v.w};
        store4(&xb[(size_t)i * 4], a);
    } else if (b < CVTX_NB + INIT_NB) {
        int i = (b - CVTX_NB) * 256 + threadIdx.x;
        if (i < N_NODES) deg[i] = 0;
        if (i < 128) { h0pad[i] = 0; h1pad[i] = 0; }
    } else if (b < CVTX_NB + INIT_NB + CVTW_NB) {
        int i = (b - CVTX_NB - INIT_NB) * 256 + threadIdx.x;
        if (i < WP_ALL) {
            const float* src; int off, ks;
            if      (i < POF_L0) { src = w_emb; off = POF_EMB; ks = 128; }
            else if (i < POF_R0) { src = wl0;   off = POF_L0;  ks = 256; }
            else if (i < POF_L1) { src = wr0;   off = POF_R0;  ks = 256; }
            else if (i < POF_R1) { src = wl1;   off = POF_L1;  ks = 256; }
            else if (i < POF_P1) { src = wr1;   off = POF_R1;  ks = 256; }
            else                 { src = wp1;   off = POF_P1;  ks = 1024; }
            int o = i - off;
            int kseg = o >> 11;
            int rem  = o & 2047;
            int n = rem >> 3, j = rem & 7;
            wbp[i] = __float2bfloat16(src[n * ks + kseg * 8 + j]);
        }
    } else {
        int i = (b - CVTX_NB - INIT_NB - CVTW_NB) * 256 + threadIdx.x;
        ebuf4[i] = make_int4(N_NODES, N_NODES, N_NODES, N_NODES);   // pad slots
    }
}

// ---------------- bucketed adjacency build ----------------
// ebuf[n*BCAP + pos]; pos from atomicAdd(&deg[n]) -> count+fill in ONE kernel.
// Arrival order varies per run; gather_agg canonicalizes via an in-register
// sort network (R29 — replaces the sort_rows launch). Slots >= deg keep the
// N_NODES pad, which sorts to the end and adds +0.0.

__global__ void fill_buckets(const int* __restrict__ src, const int* __restrict__ dst,
                             int* __restrict__ deg, int* __restrict__ ebuf, int nE) {
    int e = blockIdx.x * blockDim.x + threadIdx.x;
    if (e >= nE) return;
    int d = clampi(dst[e], N_NODES);
    int pos = atomicAdd(&deg[d], 1);
    if (pos < BCAP) ebuf[d * BCAP + pos] = clampi(src[e], N_NODES);
}

// ---------------- gather aggregation ----------------
// R29: sort_rows launch DELETED. The bucket prefix is canonicalized inside
// gather with a fully-static odd-even transposition network (pads N_NODES
// sort last, add +0.0) -> summation order = ascending src, identical to the
// old sort_rows+gather pipeline -> bit-exact, deterministic. deg<=16 (all
// but ~2 nodes): 16-net on the prefix. deg>16 (P~2e-5): load all 32 slots,
// 32-net, accumulate all (pads +0). All indices compile-time (rule #20).

__device__ __forceinline__ void cswap(int& a, int& b) {
    int lo = min(a, b), hi = max(a, b);
    a = lo; b = hi;
}

__global__ __launch_bounds__(256) void gather_agg(const __hip_bfloat16* __restrict__ h,
                                                  const int* __restrict__ deg,
                                                  const int* __restrict__ ebuf,
                                                  __hip_bfloat16* __restrict__ agg) {
    int wave = threadIdx.x >> 6, lane = threadIdx.x & 63;
    int half = lane >> 5, l32 = lane & 31;
    int n = blockIdx.x * 8 + wave * 2 + half;       // 8 nodes per 256-thr block
    bool active = (n < N_NODES);
    int nn = active ? n : 0;
    int start = nn * BCAP;

    // deg-independent issue: 16 slot indices (fixed addrs)
    int idx[16];
    #pragma unroll
    for (int i = 0; i < 16; i++) idx[i] = ebuf[start + i];
    int dg = active ? deg[nn] : 0;

    float acc[8];
    {
        float sv[8];
        load8(&h[(long long)nn * HID + l32 * 8], sv);   // self row
        #pragma unroll
        for (int k = 0; k < 8; k++) acc[k] = sv[k];
    }

    if (dg <= 16) {
        // canonical order: odd-even transposition sort of the 16 prefix slots
        #pragma unroll
        for (int ph = 0; ph < 16; ph++) {
            #pragma unroll
            for (int i = 0; i < 15; i += 2) {
                if ((ph & 1) == 0) cswap(idx[i], idx[i + 1]);
                else if (i + 2 < 16) cswap(idx[i + 1], idx[i + 2]);
            }
        }
        uint4 rawA[8], rawB[8];
        #pragma unroll
        for (int i = 0; i < 8; i++)
            rawA[i] = *(const uint4*)&h[(long long)idx[i] * HID + l32 * 8];
        #pragma unroll
        for (int i = 0; i < 8; i++)
            rawB[i] = *(const uint4*)&h[(long long)idx[8 + i] * HID + l32 * 8];
        #pragma unroll
        for (int i = 0; i < 8; i++) acc8(rawA[i], acc);
        #pragma unroll
        for (int i = 0; i < 8; i++) acc8(rawB[i], acc);
    } else {
        // rare path: full 32-slot sort (pads at end), accumulate all (+0 pads)
        int id2[32];
        #pragma unroll
        for (int i = 0; i < 16; i++) id2[i] = idx[i];
        #pragma unroll
        for (int i = 0; i < 16; i++) id2[16 + i] = ebuf[start + 16 + i];
        #pragma unroll
        for (int ph = 0; ph < 32; ph++) {
            #pragma unroll
            for (int i = 0; i < 31; i += 2) {
                if ((ph & 1) == 0) cswap(id2[i], id2[i + 1]);
                else if (i + 2 < 32) cswap(id2[i + 1], id2[i + 2]);
            }
        }
        #pragma unroll
        for (int i = 0; i < 32; i++) {
            uint4 q = *(const uint4*)&h[(long long)id2[i] * HID + l32 * 8];
            acc8(q, acc);
        }
    }

    float inv = 1.0f / (float)(dg + 1);
    #pragma unroll
    for (int k = 0; k < 8; k++) acc[k] *= inv;
    if (active) store8(&agg[(long long)n * HID + l32 * 8], acc);
}

// ============ R22/R25: K-concat LDS-staged GEMM, BK=64 (verified optimum) ============
// C = [A1|A2] @ [B1|B2]^T as ONE K=512 GEMM. Block = 128 rows x 128 cols
// (cg in {0,1}), 4 waves x (32x128) -> acc[4]; 16 MFMA per barrier.
// Grid (GX=256, 2): 512 blocks = 2/CU; cg duplicates 256 apart -> same XCD L2.
// A XOR-swizzled via pre-swizzled global source; B from packed image;
// 2-phase __syncthreads pipeline. MFMA order: t asc, k16 asc -> bit-exact.

template <int KS, bool DUAL, typename TC, bool RELU>
__global__ __launch_bounds__(256, 2) void gemm_kc(const __hip_bfloat16* __restrict__ A1,
                                                  const __hip_bfloat16* __restrict__ A2,
                                                  const __hip_bfloat16* __restrict__ Bp1,
                                                  const __hip_bfloat16* __restrict__ Bp2,
                                                  const float* __restrict__ bias,
                                                  TC* __restrict__ C, int M, int GX) {
    const int N = 256;
    const int NSTEP = (DUAL ? 2 : 1) * KS / 64;       // 64-wide K steps
    __shared__ __align__(16) short As[2][128 * 64];   // 2 x 16 KB
    __shared__ __align__(16) short Bs[2][64 * 128];   // 2 x 16 KB  (64 KB total)

    const int tid = threadIdx.x;
    const int w = tid >> 6, lane = tid & 63;
    const int half = lane >> 5, l32 = lane & 31;
    const int cg = blockIdx.y;                        // 0..1 (128-col groups)

    const short* A1s = (const short*)A1;
    const short* A2s = (const short*)A2;
    const short* B1s = (const short*)Bp1;
    const short* B2s = (const short*)Bp2;

    const int NT = (M + 127) / 128;
    for (int tile = blockIdx.x; tile < NT; tile += GX) {
        const int row0 = tile * 128;

        // stage K-step t: A 4 gloads/thread, B 4 gloads/thread
        auto stage = [&](int buf, int t) {
            const short* Asrc; const short* Bsrc; int kl;
            if (!DUAL || t < KS / 64) { Asrc = A1s; Bsrc = B1s; kl = t * 64; }
            else                      { Asrc = A2s; Bsrc = B2s; kl = t * 64 - KS; }
            #pragma unroll
            for (int i = 0; i < 4; i++) {
                int idx = i * 256 + tid;             // 0..1023
                int row = idx >> 3, b16 = idx & 7;
                int gr = row0 + row; if (gr >= M) gr = M - 1;
                gload_lds16(Asrc + (size_t)gr * KS + kl + ((b16 ^ (row & 7)) * 8),
                            (short*)&As[buf][idx * 8]);
            }
            #pragma unroll
            for (int i = 0; i < 4; i++) {
                int idx = i * 256 + tid;             // 0..1023
                int kseg = idx >> 7, col = idx & 127;
                gload_lds16(Bsrc + ((size_t)((kl >> 3) + kseg) * 256 + cg * 128 + col) * 8,
                            (short*)&Bs[buf][idx * 8]);
            }
        };

        floatx16 acc[4] = {};
        int cur = 0;
        stage(0, 0);
        __syncthreads();

        for (int t = 0; t < NSTEP; t++) {
            if (t + 1 < NSTEP) stage(cur ^ 1, t + 1);   // async, overlaps compute

            const int arow = w * 32 + l32;
            #pragma unroll
            for (int k16 = 0; k16 < 4; k16++) {
                int e = k16 * 2 + half;
                short8 a = *(const short8*)&As[cur][(arow * 8 + (e ^ (l32 & 7))) * 8];
                #pragma unroll
                for (int ct = 0; ct < 4; ct++) {
                    short8 b = *(const short8*)&Bs[cur][(e * 128 + ct * 32 + l32) * 8];
                    acc[ct] = __builtin_amdgcn_mfma_f32_32x32x16_bf16(a, b, acc[ct], 0, 0, 0);
                }
            }
            __syncthreads();                            // vmcnt(0)+lgkm+barrier
            cur ^= 1;
        }

        // epilogue: C/D col = lane&31, row = (reg&3) + 8*(reg>>2) + 4*half
        #pragma unroll
        for (int ct = 0; ct < 4; ct++) {
            int c = cg * 128 + ct * 32 + l32;
            float bc = bias[c];
            #pragma unroll
            for (int reg = 0; reg < 16; reg++) {
                int rr = row0 + w * 32 + (reg & 3) + 8 * (reg >> 2) + 4 * half;
                if (rr < M) {
                    float v = acc[ct][reg] + bc;
                    if (RELU) v = fmaxf(v, 0.0f);
                    stf(&C[(size_t)rr * N + c], v);
                }
            }
        }
    }
}

// ---------------- prediction head (R25: register-resident A, 4-step chunks) ----------------
// Each lane PRELOADS its full A-side data once: s/d row slices (cols
// quad*8 + j*32, j=0..7) as uint4 sraw[8]/draw[8]. Per step the A fragment
// is register-only: seg0/1 = reinterpret; seg2/3 = unpack->mul/absdiff->pack
// (same fp32->bf16 rounding as materialized comb -> bit-identical). B staged
// in 4-step chunks (16 KB x2 LDS) -> 8 barrier pairs, 16 MFMA/wave each.
// MFMA order: global step ascending (k ascending) -> bit-exact.

__global__ __launch_bounds__(256, 3) void pred_gemm(const __hip_bfloat16* __restrict__ h,
                                                    const int* __restrict__ src_idx,
                                                    const int* __restrict__ dst_idx,
                                                    const __hip_bfloat16* __restrict__ Bp,
                                                    const float* __restrict__ bias,
                                                    float* __restrict__ C, int M) {
    const int N = 256;
    __shared__ __align__(16) short Bs[2][16 * 64 * 8];   // 2 x 16 KB

    int w = threadIdx.x >> 6, lane = threadIdx.x & 63;
    int quad = lane >> 4, l16 = lane & 15;
    int cg = blockIdx.y;                    // 0..3 (64-col groups)
    int row0 = blockIdx.x * 64 + w * 16;    // wave owns 16 rows

    const short* Bps = (const short*)Bp;

    int rr = row0 + l16;
    int r = rr < M ? rr : M - 1;
    int sidx = clampi(src_idx[r], N_NODES);
    int didx = clampi(dst_idx[r], N_NODES);

    // one-time preload of this lane's s/d slices (64 bf16 each)
    uint4 sraw[8], draw[8];
    #pragma unroll
    for (int j = 0; j < 8; j++) {
        sraw[j] = *(const uint4*)&h[(size_t)sidx * HID + quad * 8 + j * 32];
        draw[j] = *(const uint4*)&h[(size_t)didx * HID + quad * 8 + j * 32];
    }

    // stage one 4-step chunk (16 local ksegs) of the 64-col B slice
    auto stageB = [&](int buf, int chunk) {
        #pragma unroll
        for (int i = 0; i < 4; i++) {
            int idx = i * 256 + (int)threadIdx.x;    // 0..1023
            int ks = idx >> 6, col = idx & 63;       // local kseg 0..15
            gload_lds16(Bps + ((size_t)(chunk * 16 + ks) * 256 + cg * 64 + col) * 8,
                        (short*)&Bs[buf][idx * 8]);
        }
    };

    floatx4 acc[4] = {};
    stageB(0, 0);
    __syncthreads();
    int cur = 0;

    #pragma unroll
    for (int c = 0; c < 8; c++) {             // chunk = 4 K-steps; seg = c>>1
        if (c + 1 < 8) stageB(cur ^ 1, c + 1);

        #pragma unroll
        for (int s = 0; s < 4; s++) {
            const int j = ((c & 1) ? 4 : 0) + s;   // global step t = 4c+s; j = t&7
            short8 a;
            if (c < 2) {
                a = *(const short8*)&sraw[j];
            } else if (c < 4) {
                a = *(const short8*)&draw[j];
            } else {
                float sv[8], dv[8];
                unpack8(sraw[j], sv);
                unpack8(draw[j], dv);
                __hip_bfloat16 b8[8];
                if (c < 6) {
                    #pragma unroll
                    for (int q = 0; q < 8; q++) b8[q] = __float2bfloat16(sv[q] * dv[q]);
                } else {
                    #pragma unroll
                    for (int q = 0; q < 8; q++) b8[q] = __float2bfloat16(fabsf(sv[q] - dv[q]));
                }
                a = *(const short8*)b8;
            }
            #pragma unroll
            for (int ct = 0; ct < 4; ct++) {
                short8 b = *(const short8*)&Bs[cur][((s * 4 + quad) * 64 + ct * 16 + l16) * 8];
                acc[ct] = __builtin_amdgcn_mfma_f32_16x16x32_bf16(a, b, acc[ct], 0, 0, 0);
            }
        }
        __syncthreads();
        cur ^= 1;
    }

    // epilogue: col = l16-based, row = quad*4 + i
    #pragma unroll
    for (int ct = 0; ct < 4; ct++) {
        int c = cg * 64 + ct * 16 + l16;
        float bc = bias[c];
        #pragma unroll
        for (int i = 0; i < 4; i++) {
            int r2 = row0 + quad * 4 + i;
            if (r2 < M) C[(size_t)r2 * N + c] = fmaxf(acc[ct][i] + bc, 0.0f);
        }
    }
}

__global__ __launch_bounds__(256) void pred_final(const float* __restrict__ hidden,
                                                  const float* __restrict__ wp2,
                                                  const float* __restrict__ bp2,
                                                  float* __restrict__ out) {
    int wave = threadIdx.x >> 6;
    int lane = threadIdx.x & 63;
    int row = blockIdx.x * 4 + wave;
    if (row >= N_LINKS) return;
    const float4 hv = *(const float4*)&hidden[(long long)row * HID + lane * 4];
    const float4 wv = *(const float4*)&wp2[lane * 4];
    float v = hv.x * wv.x + hv.y * wv.y + hv.z * wv.z + hv.w * wv.w;
    #pragma unroll
    for (int off = 32; off > 0; off >>= 1) v += __shfl_down(v, off, 64);
    if (lane == 0) out[row] = 1.0f / (1.0f + expf(-(v + bp2[0])));
}

// ---------------- launch ----------------

extern "C" void kernel_launch(void* const* d_in, const int* in_sizes, int n_in,
                              void* d_out, int out_size, void* d_ws, size_t ws_size,
                              hipStream_t stream) {
    const float* x          = (const float*)d_in[0];
    const int*   edge_index = (const int*)d_in[1];
    const int*   e_src      = edge_index;            // row 0
    const int*   e_dst      = edge_index + N_EDGES;  // row 1
    const int*   src_idx    = (const int*)d_in[3];
    const int*   dst_idx    = (const int*)d_in[4];
    const float* w_emb      = (const float*)d_in[5];
    const float* b_emb      = (const float*)d_in[6];
    const float* wl0        = (const float*)d_in[8];
    const float* bl0        = (const float*)d_in[9];
    const float* wr0        = (const float*)d_in[10];
    const float* wl1        = (const float*)d_in[13];
    const float* bl1        = (const float*)d_in[14];
    const float* wr1        = (const float*)d_in[15];
    const float* wp1        = (const float*)d_in[18];
    const float* bp1        = (const float*)d_in[19];
    const float* wp2        = (const float*)d_in[20];
    const float* bp2        = (const float*)d_in[21];
    float* out = (float*)d_out;

    typedef __hip_bfloat16 bf16;
    const size_t NH  = (size_t)N_NODES * HID;
    const size_t NH1 = (size_t)(N_NODES + 1) * HID;   // +1 zero row (gather pads)

    // workspace plan (~194 MB; ws proven >= 205 MB)
    char* p = (char*)d_ws;
    bf16* h0   = (bf16*)p;  p += NH1 * 2;                      // 51.2 MB (+512B)
    bf16* h1   = (bf16*)p;  p += NH1 * 2;                      // 51.2 MB (+512B)
    bf16* agg  = (bf16*)p;  p += NH * 2;                       // 51.2 MB
    bf16* xb   = (bf16*)p;  p += (size_t)N_NODES * FEAT * 2;   // 25.6 MB
    bf16* wbp  = (bf16*)p;  p += (size_t)WP_ALL * 2;           // 1.1 MB (packed)
    p = (char*)(((uintptr_t)p + 255) & ~(uintptr_t)255);
    int* deg  = (int*)p; p += (size_t)N_NODES * 4;             // 0.4 MB
    int* ebuf = (int*)p; p += (size_t)N_NODES * BCAP * 4;      // 12.8 MB
    const size_t need = (size_t)(p - (char*)d_ws);

    if (ws_size < need) {   // visible failure, no fault
        zero_f32<<<(out_size + 255) / 256, 256, 0, stream>>>(out, out_size);
        return;
    }

    // alias (region dead by the time it's reused):
    float* hidden = (float*)h1;  // [16384][256] fp32 = 16.8 MB <= 51.2

    // ---- fused prep (cvt_x | deg/pad init | weight pack | ebuf pad) ----
    prep_all<<<CVTX_NB + INIT_NB + CVTW_NB + EBUF_NB, 256, 0, stream>>>(
        (const float4*)x, xb, deg, (int*)(h0 + NH), (int*)(h1 + NH),
        w_emb, wl0, wr0, wl1, wr1, wp1, wbp, (int4*)ebuf);

    // ---- bucketed adjacency (sort_rows folded into gather_agg, R29) ----
    fill_buckets<<<(N_EDGES + 255) / 256, 256, 0, stream>>>(e_src, e_dst, deg, ebuf, N_EDGES);

    const int GX = 256;                     // 256 walkers x 2 cg = 512 blocks, 2/CU
    dim3 pgrid(GX, 2);                      // cg slow; duplicates 256 apart ->
                                            // same XCD L2 (256 % 8 == 0)

    // ---- embedding: h0 = xb @ w_emb^T + b_emb  (KS=128) ----
    gemm_kc<128, false, bf16, false><<<pgrid, 256, 0, stream>>>(
        xb, nullptr, wbp + POF_EMB, nullptr, b_emb, h0, N_NODES, GX);

    // ---- layer 0: h1 = relu(agg@wl0^T + bl0 + h0@wr0^T)  (K-concat 512) ----
    gather_agg<<<(N_NODES + 7) / 8, 256, 0, stream>>>(h0, deg, ebuf, agg);
    gemm_kc<256, true, bf16, true><<<pgrid, 256, 0, stream>>>(
        agg, h0, wbp + POF_L0, wbp + POF_R0, bl0, h1, N_NODES, GX);

    // ---- layer 1: h0 = relu(agg@wl1^T + bl1 + h1@wr1^T) ----
    gather_agg<<<(N_NODES + 7) / 8, 256, 0, stream>>>(h1, deg, ebuf, agg);
    gemm_kc<256, true, bf16, true><<<pgrid, 256, 0, stream>>>(
        agg, h1, wbp + POF_L1, wbp + POF_R1, bl1, h0, N_NODES, GX);

    // ---- prediction head (comb fused; register-resident A) ----
    dim3 pgrid2(N_LINKS / 64, 4);
    pred_gemm<<<pgrid2, 256, 0, stream>>>(
        h0, src_idx, dst_idx, wbp + POF_P1, bp1, hidden, N_LINKS);
    pred_final<<<N_LINKS / 4, 256, 0, stream>>>(hidden, wp2, bp2, out);
}